// Round 5
// baseline (533.842 us; speedup 1.0000x reference)
//
#include <hip/hip_runtime.h>
#include <math.h>
#include <stdint.h>

#define B_      2
#define S_      2048
#define HID_    2048
#define H_      16
#define D_NOPE_ 128
#define D_ROPE_ 64
#define D_V_    128
#define R_      512
#define D_Q_    192
#define NTOK    (B_ * S_)
#define EPS_    1e-6f

typedef __attribute__((ext_vector_type(8))) short bf16x8;
typedef __attribute__((ext_vector_type(4))) float f32x4;

__device__ __forceinline__ short f2bf(float x) {
    union { float f; unsigned u; } un; un.f = x;
    unsigned r = (un.u + 0x7fffu + ((un.u >> 16) & 1u)) >> 16;
    return (short)r;
}
__device__ __forceinline__ float bf2f(short s) {
    union { unsigned u; float f; } un;
    un.u = ((unsigned)(unsigned short)s) << 16;
    return un.f;
}

__device__ __forceinline__ void async_ld16(const short* gsrc, short* ldst) {
    __builtin_amdgcn_global_load_lds(
        (const __attribute__((address_space(1))) void*)gsrc,
        (__attribute__((address_space(3))) void*)ldst, 16, 0, 0);
}

// ---------------------------------------------------------------------------
// cast f32 -> bf16
// ---------------------------------------------------------------------------
__global__ __launch_bounds__(256) void castk(const float* __restrict__ in, short* __restrict__ out) {
    int i = blockIdx.x * 256 + threadIdx.x;
    float4 v = ((const float4*)in)[i];
    ushort4 o;
    o.x = (unsigned short)f2bf(v.x); o.y = (unsigned short)f2bf(v.y);
    o.z = (unsigned short)f2bf(v.z); o.w = (unsigned short)f2bf(v.w);
    ((ushort4*)out)[i] = o;
}

// ---------------------------------------------------------------------------
// W[K][Nreal] f32 -> WT[Npad][K] bf16 (rows >= Nreal zero-filled).
// ---------------------------------------------------------------------------
__global__ __launch_bounds__(256) void transpose_cast(const float* __restrict__ W,
                                                      short* __restrict__ WT,
                                                      int K, int Nreal) {
    __shared__ float T[32][33];
    const int n0 = blockIdx.x * 32, k0 = blockIdx.y * 32;
    const int t = threadIdx.x;
    const int r = t >> 3, c4 = (t & 7) * 4;
    float4 v = make_float4(0.f, 0.f, 0.f, 0.f);
    if (n0 < Nreal) v = *(const float4*)&W[(size_t)(k0 + r) * Nreal + n0 + c4];
    T[r][c4 + 0] = v.x; T[r][c4 + 1] = v.y; T[r][c4 + 2] = v.z; T[r][c4 + 3] = v.w;
    __syncthreads();
    const int n = t >> 3, k4 = (t & 7) * 4;
    ushort4 o;
    o.x = (unsigned short)f2bf(T[k4 + 0][n]);
    o.y = (unsigned short)f2bf(T[k4 + 1][n]);
    o.z = (unsigned short)f2bf(T[k4 + 2][n]);
    o.w = (unsigned short)f2bf(T[k4 + 3][n]);
    *(ushort4*)&WT[(size_t)(n0 + n) * K + k0 + k4] = o;
}

// ---------------------------------------------------------------------------
// MFMA GEMM: C[M][N] = A[M][K](bf16) @ BT[N][K](bf16). 128x128 tile, 4 waves.
// ---------------------------------------------------------------------------
template <int OUTBF>
__global__ __launch_bounds__(256) void gemm_mfma(const short* __restrict__ A,
                                                 const short* __restrict__ BT,
                                                 void* __restrict__ C,
                                                 int M, int N, int K) {
    __shared__ short As[128 * 32];
    __shared__ short Bs[128 * 32];
    const int tid = threadIdx.x;
    const int lane = tid & 63, w = tid >> 6;
    const int brow = blockIdx.y * 128, bcol = blockIdx.x * 128;

    const int o0 = w * 1024 + lane * 16;
    const int r0 = o0 >> 6, q0p = (o0 >> 4) & 3;
    const int o1 = o0 + 4096;
    const int r1 = o1 >> 6, q1p = (o1 >> 4) & 3;
    const int s0 = r0 * K + 8 * (q0p ^ ((r0 >> 1) & 3));
    const int s1 = r1 * K + 8 * (q1p ^ ((r1 >> 1) & 3));
    const short* Ab = A + (size_t)brow * K;
    const short* Bb = BT + (size_t)bcol * K;
    short* AsU0 = &As[w * 512]; short* AsU1 = &As[w * 512 + 2048];
    short* BsU0 = &Bs[w * 512]; short* BsU1 = &Bs[w * 512 + 2048];

    const int wr = w >> 1, wc = w & 1;
    const int c16 = lane & 15, g = lane >> 4;
    const int qph = (g ^ ((c16 >> 1) & 3)) * 8;

    f32x4 zero = {0.f, 0.f, 0.f, 0.f};
    f32x4 acc[4][4];
#pragma unroll
    for (int i = 0; i < 4; ++i)
#pragma unroll
        for (int j = 0; j < 4; ++j) acc[i][j] = zero;

    for (int k0 = 0; k0 < K; k0 += 32) {
        async_ld16(Ab + s0 + k0, AsU0);
        async_ld16(Ab + s1 + k0, AsU1);
        async_ld16(Bb + s0 + k0, BsU0);
        async_ld16(Bb + s1 + k0, BsU1);
        __syncthreads();
        bf16x8 af[4], bf[4];
#pragma unroll
        for (int i = 0; i < 4; ++i) {
            af[i] = *(const bf16x8*)&As[(wr * 64 + i * 16 + c16) * 32 + qph];
            bf[i] = *(const bf16x8*)&Bs[(wc * 64 + i * 16 + c16) * 32 + qph];
        }
#pragma unroll
        for (int mi = 0; mi < 4; ++mi)
#pragma unroll
            for (int ni = 0; ni < 4; ++ni)
                acc[mi][ni] = __builtin_amdgcn_mfma_f32_16x16x32_bf16(af[mi], bf[ni], acc[mi][ni], 0, 0, 0);
        __syncthreads();
    }

#pragma unroll
    for (int mi = 0; mi < 4; ++mi)
#pragma unroll
        for (int ni = 0; ni < 4; ++ni)
#pragma unroll
            for (int reg = 0; reg < 4; ++reg) {
                int row = brow + wr * 64 + mi * 16 + 4 * g + reg;
                int col = bcol + wc * 64 + ni * 16 + c16;
                if (OUTBF) ((short*)C)[(size_t)row * N + col] = f2bf(acc[mi][ni][reg]);
                else       ((float*)C)[(size_t)row * N + col] = acc[mi][ni][reg];
            }
}

// ---------------------------------------------------------------------------
// In-place RoPE on q_pe region of bf16 q. One thread per (tok, head, i<32).
// ---------------------------------------------------------------------------
__global__ __launch_bounds__(256) void rope_q_ip(short* __restrict__ qb,
                                                 const float* __restrict__ cosT,
                                                 const float* __restrict__ sinT,
                                                 const int* __restrict__ pid) {
    int gidx = blockIdx.x * 256 + threadIdx.x;   // NTOK*H*32 total
    int i = gidx & 31;
    int h = (gidx >> 5) & (H_ - 1);
    int tok = gidx >> 9;
    int pos = pid[tok];
    float c = cosT[pos * 32 + i];
    float s = sinT[pos * 32 + i];
    short* base = qb + (size_t)tok * (H_ * D_Q_) + h * D_Q_ + D_NOPE_;
    float x1 = bf2f(base[i]);
    float x2 = bf2f(base[i + 32]);
    base[i]      = f2bf(x1 * c - x2 * s);
    base[i + 32] = f2bf(x2 * c + x1 * s);
}

// ---------------------------------------------------------------------------
// LayerNorm(512) + RoPE(k_pe). ckv stride 640. Outputs bf16.
// ---------------------------------------------------------------------------
__global__ __launch_bounds__(256) void ln_rope(const float* __restrict__ ckv,
                                               const float* __restrict__ gam,
                                               const float* __restrict__ bet,
                                               const float* __restrict__ cosT,
                                               const float* __restrict__ sinT,
                                               const int* __restrict__ pid,
                                               short* __restrict__ kvcn,
                                               short* __restrict__ kpe) {
    const int tok = blockIdx.x, tid = threadIdx.x;
    const float* x = ckv + (size_t)tok * 640;
    float v0 = x[tid], v1 = x[tid + 256];
    float s = v0 + v1, sq = v0 * v0 + v1 * v1;
#pragma unroll
    for (int m = 1; m < 64; m <<= 1) { s += __shfl_xor(s, m); sq += __shfl_xor(sq, m); }
    __shared__ float ws[8];
    int wid = tid >> 6, lane = tid & 63;
    if (lane == 0) { ws[wid] = s; ws[4 + wid] = sq; }
    __syncthreads();
    s = ws[0] + ws[1] + ws[2] + ws[3];
    sq = ws[4] + ws[5] + ws[6] + ws[7];
    float mean = s * (1.f / 512.f);
    float var = sq * (1.f / 512.f) - mean * mean;
    float rstd = rsqrtf(var + EPS_);
    kvcn[(size_t)tok * 512 + tid]       = f2bf((v0 - mean) * rstd * gam[tid] + bet[tid]);
    kvcn[(size_t)tok * 512 + tid + 256] = f2bf((v1 - mean) * rstd * gam[tid + 256] + bet[tid + 256]);
    if (tid < 32) {
        int pos = pid[tok];
        float c = cosT[pos * 32 + tid], sn = sinT[pos * 32 + tid];
        float x1 = x[512 + tid], x2 = x[512 + 32 + tid];
        kpe[(size_t)tok * 64 + tid]      = f2bf(x1 * c - x2 * sn);
        kpe[(size_t)tok * 64 + 32 + tid] = f2bf(x2 * c + x1 * sn);
    }
}

// ---------------------------------------------------------------------------
// V transpose: kvb[token][h][128..255] -> Vt[b][h][d][s].
// ---------------------------------------------------------------------------
__global__ __launch_bounds__(256) void transpose_v(const short* __restrict__ kvb,
                                                   short* __restrict__ Vt) {
    __shared__ short T[64][72];
    const int s0 = blockIdx.x * 64, d0 = blockIdx.y * 64, bh = blockIdx.z;
    const int b = bh >> 4, h = bh & 15;
    const int t = threadIdx.x;
    const int r = t >> 3, c8 = (t & 7) * 8;
#pragma unroll
    for (int i = 0; i < 2; ++i) {
        int rr = r + 32 * i;
        bf16x8 v = *(const bf16x8*)&kvb[((size_t)(b * 2048 + s0 + rr) * 16 + h) * 256 + 128 + d0 + c8];
        *(bf16x8*)&T[rr][c8] = v;
    }
    __syncthreads();
#pragma unroll
    for (int i = 0; i < 2; ++i) {
        int d = r + 32 * i;
        bf16x8 o;
#pragma unroll
        for (int j = 0; j < 8; ++j) o[j] = T[c8 + j][d];
        *(bf16x8*)&Vt[((size_t)(b * 16 + h) * 128 + d0 + d) * 2048 + s0 + c8] = o;
    }
}

// ---------------------------------------------------------------------------
// MFMA flash attention. K LDS-staged (dbuf, swizzled); V + kpe direct from
// global (XCD-pinned => L2-hot). LDS = 43K -> 3 blocks/CU (12 waves).
// Grid: 1024 blocks 1-D, XCD-aware mapping. Block = 64 q-rows, 4 waves.
// ---------------------------------------------------------------------------
__global__ __launch_bounds__(256) void flash_mfma(const short* __restrict__ qb,
                                                  const short* __restrict__ kvb,
                                                  const short* __restrict__ kpe,
                                                  const short* __restrict__ Vt,
                                                  short* __restrict__ attno) {
    __shared__ short Ks[2][64 * 128];
    __shared__ short P[4][16][80];   // row stride 160B: g-groups hit disjoint banks

    // XCD-aware mapping: all q-tiles of a (b,h) on one XCD; long blocks first.
    const int flat = blockIdx.x;
    const int xcd = flat & 7, idx = flat >> 3;
    const int bh = xcd + 8 * (idx >> 5);
    const int qt = 31 - (idx & 31);
    const int b = bh >> 4, h = bh & 15;
    const int q0 = qt * 64;

    const int tid = threadIdx.x, lane = tid & 63, w = tid >> 6;
    const int c16 = lane & 15, g = lane >> 4, g8 = g * 8;
    const float scale = 0.07216878364870323f;   // 1/sqrt(192)

    const int qrow = q0 + w * 16;
    const size_t qbase = ((size_t)(b * 2048 + qrow + c16) * 16 + h) * 192 + g8;
    bf16x8 qf[6];
#pragma unroll
    for (int ks = 0; ks < 6; ++ks) qf[ks] = *(const bf16x8*)(qb + qbase + 32 * ks);

    f32x4 zero = {0.f, 0.f, 0.f, 0.f};
    f32x4 acc[8];
#pragma unroll
    for (int i = 0; i < 8; ++i) acc[i] = zero;
    float mreg[4] = {-INFINITY, -INFINITY, -INFINITY, -INFINITY};
    float lreg[4] = {0.f, 0.f, 0.f, 0.f};

#define STAGE_K(BUF, K0)                                                              \
    {                                                                                 \
        _Pragma("unroll")                                                             \
        for (int rnd = 0; rnd < 4; ++rnd) {                                           \
            int o = rnd * 4096 + w * 1024 + lane * 16;                                \
            int r = o >> 8, qs = (o >> 4) & 15;                                       \
            int cc = qs ^ (r & 7);                                                    \
            const short* src = kvb + ((size_t)((b * 2048 + (K0) + r) * 16 + h)) * 256 \
                               + cc * 8;                                              \
            async_ld16(src, &Ks[BUF][(rnd * 4096 + w * 1024) >> 1]);                  \
        }                                                                             \
    }

    const int nt = qt + 1;
    STAGE_K(0, 0);
    __syncthreads();
    int cur = 0;

    for (int kt = 0; kt < nt; ++kt) {
        const int k0 = kt * 64;
        if (kt + 1 < nt) STAGE_K(cur ^ 1, k0 + 64);

        f32x4 sc[4];
#pragma unroll
        for (int i = 0; i < 4; ++i) sc[i] = zero;

        // QK^T nope from LDS (swizzled reads)
        __builtin_amdgcn_s_setprio(1);
#pragma unroll
        for (int ks = 0; ks < 4; ++ks)
#pragma unroll
            for (int nb = 0; nb < 4; ++nb) {
                int row = nb * 16 + c16;
                bf16x8 kf = *(const bf16x8*)&Ks[cur][row * 128 + (((g + 4 * ks) ^ (row & 7)) << 3)];
                sc[nb] = __builtin_amdgcn_mfma_f32_16x16x32_bf16(qf[ks], kf, sc[nb], 0, 0, 0);
            }
        // pe part straight from global (kpe tiny + shared across heads -> L2-hot)
        const size_t pb = (size_t)(b * 2048 + k0 + c16) * 64 + g8;
#pragma unroll
        for (int ks = 0; ks < 2; ++ks)
#pragma unroll
            for (int nb = 0; nb < 4; ++nb) {
                bf16x8 kf = *(const bf16x8*)(kpe + pb + (size_t)nb * 16 * 64 + ks * 32);
                sc[nb] = __builtin_amdgcn_mfma_f32_16x16x32_bf16(qf[4 + ks], kf, sc[nb], 0, 0, 0);
            }
        __builtin_amdgcn_s_setprio(0);

#pragma unroll
        for (int nb = 0; nb < 4; ++nb) sc[nb] *= scale;

        if (kt == nt - 1) {
#pragma unroll
            for (int nb = 0; nb < 4; ++nb)
#pragma unroll
                for (int reg = 0; reg < 4; ++reg) {
                    int col = k0 + nb * 16 + c16;
                    int row = qrow + 4 * g + reg;
                    if (col > row) sc[nb][reg] = -INFINITY;
                }
        }

        // online softmax
        float rmax[4], rsum[4], mnew[4], alpha[4];
#pragma unroll
        for (int reg = 0; reg < 4; ++reg)
            rmax[reg] = fmaxf(fmaxf(sc[0][reg], sc[1][reg]), fmaxf(sc[2][reg], sc[3][reg]));
#pragma unroll
        for (int m = 1; m < 16; m <<= 1)
#pragma unroll
            for (int reg = 0; reg < 4; ++reg)
                rmax[reg] = fmaxf(rmax[reg], __shfl_xor(rmax[reg], m));
#pragma unroll
        for (int reg = 0; reg < 4; ++reg) {
            mnew[reg] = fmaxf(mreg[reg], rmax[reg]);
            alpha[reg] = __expf(mreg[reg] - mnew[reg]);
            mreg[reg] = mnew[reg];
            rsum[reg] = 0.f;
        }
#pragma unroll
        for (int nb = 0; nb < 4; ++nb)
#pragma unroll
            for (int reg = 0; reg < 4; ++reg) {
                float p = __expf(sc[nb][reg] - mnew[reg]);
                sc[nb][reg] = p;
                rsum[reg] += p;
            }
#pragma unroll
        for (int m = 1; m < 16; m <<= 1)
#pragma unroll
            for (int reg = 0; reg < 4; ++reg)
                rsum[reg] += __shfl_xor(rsum[reg], m);
#pragma unroll
        for (int reg = 0; reg < 4; ++reg) lreg[reg] = lreg[reg] * alpha[reg] + rsum[reg];
#pragma unroll
        for (int nb = 0; nb < 8; ++nb)
#pragma unroll
            for (int reg = 0; reg < 4; ++reg) acc[nb][reg] *= alpha[reg];

        // P -> LDS (C/D layout -> A layout)
#pragma unroll
        for (int nb = 0; nb < 4; ++nb)
#pragma unroll
            for (int reg = 0; reg < 4; ++reg)
                P[w][4 * g + reg][nb * 16 + c16] = f2bf(sc[nb][reg]);

        // PV: V fragments direct from global Vt (L2-hot, shared by 4 waves)
        const size_t vb = ((size_t)(b * 16 + h) * 128 + c16) * 2048 + k0 + g8;
        __builtin_amdgcn_s_setprio(1);
#pragma unroll
        for (int ks = 0; ks < 2; ++ks) {
            bf16x8 pf = *(const bf16x8*)&P[w][c16][ks * 32 + g8];
#pragma unroll
            for (int nb = 0; nb < 8; ++nb) {
                bf16x8 vf = *(const bf16x8*)(Vt + vb + (size_t)nb * 16 * 2048 + ks * 32);
                acc[nb] = __builtin_amdgcn_mfma_f32_16x16x32_bf16(pf, vf, acc[nb], 0, 0, 0);
            }
        }
        __builtin_amdgcn_s_setprio(0);

        __syncthreads();   // drains stage vmcnt + all waves done with buffers
        cur ^= 1;
    }
#undef STAGE_K

    float inv[4];
#pragma unroll
    for (int reg = 0; reg < 4; ++reg) inv[reg] = 1.f / lreg[reg];
#pragma unroll
    for (int nb = 0; nb < 8; ++nb)
#pragma unroll
        for (int reg = 0; reg < 4; ++reg)
            attno[((size_t)(b * 2048 + qrow + 4 * g + reg) * 16 + h) * 128 + nb * 16 + c16] =
                f2bf(acc[nb][reg] * inv[reg]);
}

// ---------------------------------------------------------------------------
extern "C" void kernel_launch(void* const* d_in, const int* in_sizes, int n_in,
                              void* d_out, int out_size, void* d_ws, size_t ws_size,
                              hipStream_t stream) {
    const float* hidden = (const float*)d_in[0];
    const float* cosT   = (const float*)d_in[1];
    const float* sinT   = (const float*)d_in[2];
    const int*   pid    = (const int*)d_in[3];
    const float* Wq     = (const float*)d_in[4];
    const float* Wkv_a  = (const float*)d_in[5];
    const float* ln_g   = (const float*)d_in[6];
    const float* ln_b   = (const float*)d_in[7];
    const float* Wkv_b  = (const float*)d_in[8];
    const float* Wo     = (const float*)d_in[9];
    float* out = (float*)d_out;

    char* p = (char*)d_ws;
    short* hid_bf = (short*)p;               p += (size_t)NTOK * 2048 * 2;
    short* WqT    = (short*)p;               p += (size_t)3072 * 2048 * 2;
    short* WkaT   = (short*)p;               p += (size_t)640 * 2048 * 2;
    short* WkbT   = (short*)p;               p += (size_t)4096 * 512 * 2;
    short* WoT    = (short*)p;               p += (size_t)2048 * 2048 * 2;
    char*  big    = p;                       p += (size_t)NTOK * 3072 * 4;
    short* qbuf   = (short*)p;               p += (size_t)NTOK * 3072 * 2;
    short* kvcn   = (short*)p;               p += (size_t)NTOK * 512 * 2;
    short* kpe    = (short*)p;               p += (size_t)NTOK * 64 * 2;
    short* kvb    = (short*)p;               p += (size_t)NTOK * 4096 * 2;

    float* ckv   = (float*)big;
    short* Vt    = (short*)(big + (size_t)NTOK * 640 * 4);
    short* attno = (short*)(big + (size_t)NTOK * 640 * 4 + (size_t)2 * 16 * 128 * 2048 * 2);

    castk<<<8192, 256, 0, stream>>>(hidden, hid_bf);
    transpose_cast<<<dim3(96, 64), 256, 0, stream>>>(Wq, WqT, 2048, 3072);
    transpose_cast<<<dim3(20, 64), 256, 0, stream>>>(Wkv_a, WkaT, 2048, 576);
    transpose_cast<<<dim3(128, 16), 256, 0, stream>>>(Wkv_b, WkbT, 512, 4096);
    transpose_cast<<<dim3(64, 64), 256, 0, stream>>>(Wo, WoT, 2048, 2048);

    // 1. q = hidden @ Wq -> bf16 directly
    gemm_mfma<1><<<dim3(24, 32), 256, 0, stream>>>(hid_bf, WqT, qbuf, 4096, 3072, 2048);
    // 2. RoPE in place on q_pe (bf16)
    rope_q_ip<<<(NTOK * H_ * 32) / 256, 256, 0, stream>>>(qbuf, cosT, sinT, pid);
    // 3. ckv = hidden @ Wkv_a (f32 out, N padded to 640)
    gemm_mfma<0><<<dim3(5, 32), 256, 0, stream>>>(hid_bf, WkaT, ckv, 4096, 640, 2048);
    // 4. LayerNorm + RoPE(k_pe) -> bf16
    ln_rope<<<NTOK, 256, 0, stream>>>(ckv, ln_g, ln_b, cosT, sinT, pid, kvcn, kpe);
    // 5. kv = kvcn @ Wkv_b (bf16 out)
    gemm_mfma<1><<<dim3(32, 32), 256, 0, stream>>>(kvcn, WkbT, kvb, 4096, 4096, 512);
    // 6. V transpose
    transpose_v<<<dim3(32, 2, 32), 256, 0, stream>>>(kvb, Vt);
    // 7. flash attention
    flash_mfma<<<1024, 256, 0, stream>>>(qbuf, kvb, kpe, Vt, attno);
    // 8. out = attno @ Wo (f32 out)
    gemm_mfma<0><<<dim3(16, 32), 256, 0, stream>>>(attno, WoT, out, 4096, 2048, 2048);
}

// Round 6
// 420.006 us; speedup vs baseline: 1.2710x; 1.2710x over previous
//
#include <hip/hip_runtime.h>
#include <math.h>
#include <stdint.h>

#define B_      2
#define S_      2048
#define HID_    2048
#define H_      16
#define D_NOPE_ 128
#define D_ROPE_ 64
#define D_V_    128
#define R_      512
#define D_Q_    192
#define NTOK    (B_ * S_)
#define EPS_    1e-6f

typedef __attribute__((ext_vector_type(8))) short bf16x8;
typedef __attribute__((ext_vector_type(4))) float f32x4;

__device__ __forceinline__ short f2bf(float x) {
    union { float f; unsigned u; } un; un.f = x;
    unsigned r = (un.u + 0x7fffu + ((un.u >> 16) & 1u)) >> 16;
    return (short)r;
}
__device__ __forceinline__ float bf2f(short s) {
    union { unsigned u; float f; } un;
    un.u = ((unsigned)(unsigned short)s) << 16;
    return un.f;
}

__device__ __forceinline__ void async_ld16(const short* gsrc, short* ldst) {
    __builtin_amdgcn_global_load_lds(
        (const __attribute__((address_space(1))) void*)gsrc,
        (__attribute__((address_space(3))) void*)ldst, 16, 0, 0);
}

// ---------------------------------------------------------------------------
// cast f32 -> bf16
// ---------------------------------------------------------------------------
__global__ __launch_bounds__(256) void castk(const float* __restrict__ in, short* __restrict__ out) {
    int i = blockIdx.x * 256 + threadIdx.x;
    float4 v = ((const float4*)in)[i];
    ushort4 o;
    o.x = (unsigned short)f2bf(v.x); o.y = (unsigned short)f2bf(v.y);
    o.z = (unsigned short)f2bf(v.z); o.w = (unsigned short)f2bf(v.w);
    ((ushort4*)out)[i] = o;
}

// ---------------------------------------------------------------------------
// W[K][Nreal] f32 -> WT[Npad][K] bf16 (rows >= Nreal zero-filled).
// ---------------------------------------------------------------------------
__global__ __launch_bounds__(256) void transpose_cast(const float* __restrict__ W,
                                                      short* __restrict__ WT,
                                                      int K, int Nreal) {
    __shared__ float T[32][33];
    const int n0 = blockIdx.x * 32, k0 = blockIdx.y * 32;
    const int t = threadIdx.x;
    const int r = t >> 3, c4 = (t & 7) * 4;
    float4 v = make_float4(0.f, 0.f, 0.f, 0.f);
    if (n0 < Nreal) v = *(const float4*)&W[(size_t)(k0 + r) * Nreal + n0 + c4];
    T[r][c4 + 0] = v.x; T[r][c4 + 1] = v.y; T[r][c4 + 2] = v.z; T[r][c4 + 3] = v.w;
    __syncthreads();
    const int n = t >> 3, k4 = (t & 7) * 4;
    ushort4 o;
    o.x = (unsigned short)f2bf(T[k4 + 0][n]);
    o.y = (unsigned short)f2bf(T[k4 + 1][n]);
    o.z = (unsigned short)f2bf(T[k4 + 2][n]);
    o.w = (unsigned short)f2bf(T[k4 + 3][n]);
    *(ushort4*)&WT[(size_t)(n0 + n) * K + k0 + k4] = o;
}

// ---------------------------------------------------------------------------
// MFMA GEMM: C[M][N] = A[M][K](bf16) @ BT[N][K](bf16). 128x128 tile, 4 waves.
// ---------------------------------------------------------------------------
template <int OUTBF>
__global__ __launch_bounds__(256) void gemm_mfma(const short* __restrict__ A,
                                                 const short* __restrict__ BT,
                                                 void* __restrict__ C,
                                                 int M, int N, int K) {
    __shared__ short As[128 * 32];
    __shared__ short Bs[128 * 32];
    const int tid = threadIdx.x;
    const int lane = tid & 63, w = tid >> 6;
    const int brow = blockIdx.y * 128, bcol = blockIdx.x * 128;

    const int o0 = w * 1024 + lane * 16;
    const int r0 = o0 >> 6, q0p = (o0 >> 4) & 3;
    const int o1 = o0 + 4096;
    const int r1 = o1 >> 6, q1p = (o1 >> 4) & 3;
    const int s0 = r0 * K + 8 * (q0p ^ ((r0 >> 1) & 3));
    const int s1 = r1 * K + 8 * (q1p ^ ((r1 >> 1) & 3));
    const short* Ab = A + (size_t)brow * K;
    const short* Bb = BT + (size_t)bcol * K;
    short* AsU0 = &As[w * 512]; short* AsU1 = &As[w * 512 + 2048];
    short* BsU0 = &Bs[w * 512]; short* BsU1 = &Bs[w * 512 + 2048];

    const int wr = w >> 1, wc = w & 1;
    const int c16 = lane & 15, g = lane >> 4;
    const int qph = (g ^ ((c16 >> 1) & 3)) * 8;

    f32x4 zero = {0.f, 0.f, 0.f, 0.f};
    f32x4 acc[4][4];
#pragma unroll
    for (int i = 0; i < 4; ++i)
#pragma unroll
        for (int j = 0; j < 4; ++j) acc[i][j] = zero;

    for (int k0 = 0; k0 < K; k0 += 32) {
        async_ld16(Ab + s0 + k0, AsU0);
        async_ld16(Ab + s1 + k0, AsU1);
        async_ld16(Bb + s0 + k0, BsU0);
        async_ld16(Bb + s1 + k0, BsU1);
        __syncthreads();
        bf16x8 af[4], bf[4];
#pragma unroll
        for (int i = 0; i < 4; ++i) {
            af[i] = *(const bf16x8*)&As[(wr * 64 + i * 16 + c16) * 32 + qph];
            bf[i] = *(const bf16x8*)&Bs[(wc * 64 + i * 16 + c16) * 32 + qph];
        }
#pragma unroll
        for (int mi = 0; mi < 4; ++mi)
#pragma unroll
            for (int ni = 0; ni < 4; ++ni)
                acc[mi][ni] = __builtin_amdgcn_mfma_f32_16x16x32_bf16(af[mi], bf[ni], acc[mi][ni], 0, 0, 0);
        __syncthreads();
    }

#pragma unroll
    for (int mi = 0; mi < 4; ++mi)
#pragma unroll
        for (int ni = 0; ni < 4; ++ni)
#pragma unroll
            for (int reg = 0; reg < 4; ++reg) {
                int row = brow + wr * 64 + mi * 16 + 4 * g + reg;
                int col = bcol + wc * 64 + ni * 16 + c16;
                if (OUTBF) ((short*)C)[(size_t)row * N + col] = f2bf(acc[mi][ni][reg]);
                else       ((float*)C)[(size_t)row * N + col] = acc[mi][ni][reg];
            }
}

// ---------------------------------------------------------------------------
// In-place RoPE on q_pe region of bf16 q.
// ---------------------------------------------------------------------------
__global__ __launch_bounds__(256) void rope_q_ip(short* __restrict__ qb,
                                                 const float* __restrict__ cosT,
                                                 const float* __restrict__ sinT,
                                                 const int* __restrict__ pid) {
    int gidx = blockIdx.x * 256 + threadIdx.x;
    int i = gidx & 31;
    int h = (gidx >> 5) & (H_ - 1);
    int tok = gidx >> 9;
    int pos = pid[tok];
    float c = cosT[pos * 32 + i];
    float s = sinT[pos * 32 + i];
    short* base = qb + (size_t)tok * (H_ * D_Q_) + h * D_Q_ + D_NOPE_;
    float x1 = bf2f(base[i]);
    float x2 = bf2f(base[i + 32]);
    base[i]      = f2bf(x1 * c - x2 * s);
    base[i + 32] = f2bf(x2 * c + x1 * s);
}

// ---------------------------------------------------------------------------
// LayerNorm(512) + RoPE(k_pe). ckv stride 640. Outputs bf16.
// ---------------------------------------------------------------------------
__global__ __launch_bounds__(256) void ln_rope(const float* __restrict__ ckv,
                                               const float* __restrict__ gam,
                                               const float* __restrict__ bet,
                                               const float* __restrict__ cosT,
                                               const float* __restrict__ sinT,
                                               const int* __restrict__ pid,
                                               short* __restrict__ kvcn,
                                               short* __restrict__ kpe) {
    const int tok = blockIdx.x, tid = threadIdx.x;
    const float* x = ckv + (size_t)tok * 640;
    float v0 = x[tid], v1 = x[tid + 256];
    float s = v0 + v1, sq = v0 * v0 + v1 * v1;
#pragma unroll
    for (int m = 1; m < 64; m <<= 1) { s += __shfl_xor(s, m); sq += __shfl_xor(sq, m); }
    __shared__ float ws[8];
    int wid = tid >> 6, lane = tid & 63;
    if (lane == 0) { ws[wid] = s; ws[4 + wid] = sq; }
    __syncthreads();
    s = ws[0] + ws[1] + ws[2] + ws[3];
    sq = ws[4] + ws[5] + ws[6] + ws[7];
    float mean = s * (1.f / 512.f);
    float var = sq * (1.f / 512.f) - mean * mean;
    float rstd = rsqrtf(var + EPS_);
    kvcn[(size_t)tok * 512 + tid]       = f2bf((v0 - mean) * rstd * gam[tid] + bet[tid]);
    kvcn[(size_t)tok * 512 + tid + 256] = f2bf((v1 - mean) * rstd * gam[tid + 256] + bet[tid + 256]);
    if (tid < 32) {
        int pos = pid[tok];
        float c = cosT[pos * 32 + tid], sn = sinT[pos * 32 + tid];
        float x1 = x[512 + tid], x2 = x[512 + 32 + tid];
        kpe[(size_t)tok * 64 + tid]      = f2bf(x1 * c - x2 * sn);
        kpe[(size_t)tok * 64 + 32 + tid] = f2bf(x2 * c + x1 * sn);
    }
}

// ---------------------------------------------------------------------------
// V transpose: kvb[token][h][128..255] -> Vt[b][h][d][s].
// ---------------------------------------------------------------------------
__global__ __launch_bounds__(256) void transpose_v(const short* __restrict__ kvb,
                                                   short* __restrict__ Vt) {
    __shared__ short T[64][72];
    const int s0 = blockIdx.x * 64, d0 = blockIdx.y * 64, bh = blockIdx.z;
    const int b = bh >> 4, h = bh & 15;
    const int t = threadIdx.x;
    const int r = t >> 3, c8 = (t & 7) * 8;
#pragma unroll
    for (int i = 0; i < 2; ++i) {
        int rr = r + 32 * i;
        bf16x8 v = *(const bf16x8*)&kvb[((size_t)(b * 2048 + s0 + rr) * 16 + h) * 256 + 128 + d0 + c8];
        *(bf16x8*)&T[rr][c8] = v;
    }
    __syncthreads();
#pragma unroll
    for (int i = 0; i < 2; ++i) {
        int d = r + 32 * i;
        bf16x8 o;
#pragma unroll
        for (int j = 0; j < 8; ++j) o[j] = T[c8 + j][d];
        *(bf16x8*)&Vt[((size_t)(b * 16 + h) * 128 + d0 + d) * 2048 + s0 + c8] = o;
    }
}

// ---------------------------------------------------------------------------
// MFMA flash attention. K+V LDS-staged (dbuf, swizzled source, rule 21).
// exp2-domain softmax + defer-rescale (T13) + issue-early pe loads (T14).
// Grid: 1024 blocks 1-D, XCD-aware mapping. Block = 64 q-rows, 4 waves.
// ---------------------------------------------------------------------------
__global__ __launch_bounds__(256) void flash_mfma(const short* __restrict__ qb,
                                                  const short* __restrict__ kvb,
                                                  const short* __restrict__ kpe,
                                                  const short* __restrict__ Vt,
                                                  short* __restrict__ attno) {
    __shared__ short Ks[2][64 * 128];
    __shared__ short Vs[2][128 * 64];
    __shared__ short P[4][16][72];

    // XCD-aware mapping: all q-tiles of a (b,h) on one XCD; long blocks first.
    const int flat = blockIdx.x;
    const int xcd = flat & 7, idx = flat >> 3;
    const int bh = xcd + 8 * (idx >> 5);
    const int qt = 31 - (idx & 31);
    const int b = bh >> 4, h = bh & 15;
    const int q0 = qt * 64;

    const int tid = threadIdx.x, lane = tid & 63, w = tid >> 6;
    const int c16 = lane & 15, g = lane >> 4, g8 = g * 8;
    // 1/sqrt(192) * log2(e): softmax runs in base-2 domain (v_exp_f32 IS 2^x)
    const float SC2 = 0.10412063f;

    const int qrow = q0 + w * 16;
    const size_t qbase = ((size_t)(b * 2048 + qrow + c16) * 16 + h) * 192 + g8;
    bf16x8 qf[6];
#pragma unroll
    for (int ks = 0; ks < 6; ++ks) qf[ks] = *(const bf16x8*)(qb + qbase + 32 * ks);

    f32x4 zero = {0.f, 0.f, 0.f, 0.f};
    f32x4 acc[8];
#pragma unroll
    for (int i = 0; i < 8; ++i) acc[i] = zero;
    float mreg[4] = {-INFINITY, -INFINITY, -INFINITY, -INFINITY};
    float lreg[4] = {0.f, 0.f, 0.f, 0.f};

    // ---- running stage pointers (strength-reduced addressing) ----
    const int o = w * 1024 + lane * 16;
    const short* kPtr[4];
    const short* vPtr[4];
#pragma unroll
    for (int rnd = 0; rnd < 4; ++rnd) {
        int ok = rnd * 4096 + o;
        int rK = ok >> 8, ccK = ((ok >> 4) & 15) ^ (rK & 7);
        kPtr[rnd] = kvb + ((size_t)((b * 2048 + rK) * 16 + h)) * 256 + ccK * 8;
        int rV = ok >> 7, ccV = ((ok >> 4) & 7) ^ (rV & 7);
        vPtr[rnd] = Vt + ((size_t)((b * 16 + h) * 128 + rV)) * 2048 + ccV * 8;
    }
    const short* peP = kpe + (size_t)(b * 2048 + c16) * 64 + g8;

#define STAGE(BUF)                                                         \
    {                                                                      \
        _Pragma("unroll")                                                  \
        for (int rnd = 0; rnd < 4; ++rnd) {                                \
            async_ld16(kPtr[rnd], &Ks[BUF][(rnd * 4096 + w * 1024) >> 1]); \
            kPtr[rnd] += 64 * 4096;                                        \
        }                                                                  \
        _Pragma("unroll")                                                  \
        for (int rnd = 0; rnd < 4; ++rnd) {                                \
            async_ld16(vPtr[rnd], &Vs[BUF][(rnd * 4096 + w * 1024) >> 1]); \
            vPtr[rnd] += 64;                                               \
        }                                                                  \
    }

    const int nt = qt + 1;
    STAGE(0);
    __syncthreads();
    int cur = 0;

    for (int kt = 0; kt < nt; ++kt) {
        const int k0 = kt * 64;

        // T14: issue pe fragment loads early — latency hides under QK-nope MFMAs
        bf16x8 pe[2][4];
#pragma unroll
        for (int ks = 0; ks < 2; ++ks)
#pragma unroll
            for (int nb = 0; nb < 4; ++nb)
                pe[ks][nb] = *(const bf16x8*)(peP + (size_t)nb * 16 * 64 + ks * 32);
        peP += 64 * 64;

        if (kt + 1 < nt) STAGE(cur ^ 1);

        f32x4 sc[4];
#pragma unroll
        for (int i = 0; i < 4; ++i) sc[i] = zero;

        // QK^T nope from LDS (swizzled reads)
        __builtin_amdgcn_s_setprio(1);
#pragma unroll
        for (int ks = 0; ks < 4; ++ks)
#pragma unroll
            for (int nb = 0; nb < 4; ++nb) {
                int row = nb * 16 + c16;
                bf16x8 kf = *(const bf16x8*)&Ks[cur][row * 128 + (((g + 4 * ks) ^ (row & 7)) << 3)];
                sc[nb] = __builtin_amdgcn_mfma_f32_16x16x32_bf16(qf[ks], kf, sc[nb], 0, 0, 0);
            }
#pragma unroll
        for (int ks = 0; ks < 2; ++ks)
#pragma unroll
            for (int nb = 0; nb < 4; ++nb)
                sc[nb] = __builtin_amdgcn_mfma_f32_16x16x32_bf16(qf[4 + ks], pe[ks][nb], sc[nb], 0, 0, 0);
        __builtin_amdgcn_s_setprio(0);

#pragma unroll
        for (int nb = 0; nb < 4; ++nb) sc[nb] *= SC2;

        if (kt == nt - 1) {
#pragma unroll
            for (int nb = 0; nb < 4; ++nb)
#pragma unroll
                for (int reg = 0; reg < 4; ++reg) {
                    int col = k0 + nb * 16 + c16;
                    int row = qrow + 4 * g + reg;
                    if (col > row) sc[nb][reg] = -INFINITY;
                }
        }

        // online softmax, base-2 domain, defer-rescale (T13, THR=8)
        float rmax[4];
#pragma unroll
        for (int reg = 0; reg < 4; ++reg)
            rmax[reg] = fmaxf(fmaxf(sc[0][reg], sc[1][reg]), fmaxf(sc[2][reg], sc[3][reg]));
#pragma unroll
        for (int m = 1; m < 16; m <<= 1)
#pragma unroll
            for (int reg = 0; reg < 4; ++reg)
                rmax[reg] = fmaxf(rmax[reg], __shfl_xor(rmax[reg], m));

        float grow = rmax[0] - mreg[0];
#pragma unroll
        for (int reg = 1; reg < 4; ++reg) grow = fmaxf(grow, rmax[reg] - mreg[reg]);
        if (__any(grow > 8.f)) {
#pragma unroll
            for (int reg = 0; reg < 4; ++reg) {
                float mnew = fmaxf(mreg[reg], rmax[reg]);
                float alpha = exp2f(mreg[reg] - mnew);
                mreg[reg] = mnew;
                lreg[reg] *= alpha;
#pragma unroll
                for (int nb = 0; nb < 8; ++nb) acc[nb][reg] *= alpha;
            }
        }

        float rsum[4] = {0.f, 0.f, 0.f, 0.f};
#pragma unroll
        for (int nb = 0; nb < 4; ++nb)
#pragma unroll
            for (int reg = 0; reg < 4; ++reg) {
                float pv = exp2f(sc[nb][reg] - mreg[reg]);
                sc[nb][reg] = pv;
                rsum[reg] += pv;
            }
#pragma unroll
        for (int m = 1; m < 16; m <<= 1)
#pragma unroll
            for (int reg = 0; reg < 4; ++reg)
                rsum[reg] += __shfl_xor(rsum[reg], m);
#pragma unroll
        for (int reg = 0; reg < 4; ++reg) lreg[reg] += rsum[reg];

        // P -> LDS (C/D layout -> A layout)
#pragma unroll
        for (int nb = 0; nb < 4; ++nb)
#pragma unroll
            for (int reg = 0; reg < 4; ++reg)
                P[w][4 * g + reg][nb * 16 + c16] = f2bf(sc[nb][reg]);

        // PV from LDS V (swizzled reads)
        __builtin_amdgcn_s_setprio(1);
#pragma unroll
        for (int ks = 0; ks < 2; ++ks) {
            bf16x8 pf = *(const bf16x8*)&P[w][c16][ks * 32 + g8];
#pragma unroll
            for (int nb = 0; nb < 8; ++nb) {
                int row = nb * 16 + c16;
                bf16x8 vf = *(const bf16x8*)&Vs[cur][row * 64 + (((g + 4 * ks) ^ (row & 7)) << 3)];
                acc[nb] = __builtin_amdgcn_mfma_f32_16x16x32_bf16(pf, vf, acc[nb], 0, 0, 0);
            }
        }
        __builtin_amdgcn_s_setprio(0);

        __syncthreads();   // drains stage vmcnt + all waves done with buffers
        cur ^= 1;
    }
#undef STAGE

    float inv[4];
#pragma unroll
    for (int reg = 0; reg < 4; ++reg) inv[reg] = 1.f / lreg[reg];
#pragma unroll
    for (int nb = 0; nb < 8; ++nb)
#pragma unroll
        for (int reg = 0; reg < 4; ++reg)
            attno[((size_t)(b * 2048 + qrow + 4 * g + reg) * 16 + h) * 128 + nb * 16 + c16] =
                f2bf(acc[nb][reg] * inv[reg]);
}

// ---------------------------------------------------------------------------
extern "C" void kernel_launch(void* const* d_in, const int* in_sizes, int n_in,
                              void* d_out, int out_size, void* d_ws, size_t ws_size,
                              hipStream_t stream) {
    const float* hidden = (const float*)d_in[0];
    const float* cosT   = (const float*)d_in[1];
    const float* sinT   = (const float*)d_in[2];
    const int*   pid    = (const int*)d_in[3];
    const float* Wq     = (const float*)d_in[4];
    const float* Wkv_a  = (const float*)d_in[5];
    const float* ln_g   = (const float*)d_in[6];
    const float* ln_b   = (const float*)d_in[7];
    const float* Wkv_b  = (const float*)d_in[8];
    const float* Wo     = (const float*)d_in[9];
    float* out = (float*)d_out;

    char* p = (char*)d_ws;
    short* hid_bf = (short*)p;               p += (size_t)NTOK * 2048 * 2;
    short* WqT    = (short*)p;               p += (size_t)3072 * 2048 * 2;
    short* WkaT   = (short*)p;               p += (size_t)640 * 2048 * 2;
    short* WkbT   = (short*)p;               p += (size_t)4096 * 512 * 2;
    short* WoT    = (short*)p;               p += (size_t)2048 * 2048 * 2;
    char*  big    = p;                       p += (size_t)NTOK * 3072 * 4;
    short* qbuf   = (short*)p;               p += (size_t)NTOK * 3072 * 2;
    short* kvcn   = (short*)p;               p += (size_t)NTOK * 512 * 2;
    short* kpe    = (short*)p;               p += (size_t)NTOK * 64 * 2;
    short* kvb    = (short*)p;               p += (size_t)NTOK * 4096 * 2;

    float* ckv   = (float*)big;
    short* Vt    = (short*)(big + (size_t)NTOK * 640 * 4);
    short* attno = (short*)(big + (size_t)NTOK * 640 * 4 + (size_t)2 * 16 * 128 * 2048 * 2);

    castk<<<8192, 256, 0, stream>>>(hidden, hid_bf);
    transpose_cast<<<dim3(96, 64), 256, 0, stream>>>(Wq, WqT, 2048, 3072);
    transpose_cast<<<dim3(20, 64), 256, 0, stream>>>(Wkv_a, WkaT, 2048, 576);
    transpose_cast<<<dim3(128, 16), 256, 0, stream>>>(Wkv_b, WkbT, 512, 4096);
    transpose_cast<<<dim3(64, 64), 256, 0, stream>>>(Wo, WoT, 2048, 2048);

    // 1. q = hidden @ Wq -> bf16 directly
    gemm_mfma<1><<<dim3(24, 32), 256, 0, stream>>>(hid_bf, WqT, qbuf, 4096, 3072, 2048);
    // 2. RoPE in place on q_pe (bf16)
    rope_q_ip<<<(NTOK * H_ * 32) / 256, 256, 0, stream>>>(qbuf, cosT, sinT, pid);
    // 3. ckv = hidden @ Wkv_a (f32 out, N padded to 640)
    gemm_mfma<0><<<dim3(5, 32), 256, 0, stream>>>(hid_bf, WkaT, ckv, 4096, 640, 2048);
    // 4. LayerNorm + RoPE(k_pe) -> bf16
    ln_rope<<<NTOK, 256, 0, stream>>>(ckv, ln_g, ln_b, cosT, sinT, pid, kvcn, kpe);
    // 5. kv = kvcn @ Wkv_b (bf16 out)
    gemm_mfma<1><<<dim3(32, 32), 256, 0, stream>>>(kvcn, WkbT, kvb, 4096, 4096, 512);
    // 6. V transpose
    transpose_v<<<dim3(32, 2, 32), 256, 0, stream>>>(kvb, Vt);
    // 7. flash attention
    flash_mfma<<<1024, 256, 0, stream>>>(qbuf, kvb, kpe, Vt, attno);
    // 8. out = attno @ Wo (f32 out)
    gemm_mfma<0><<<dim3(16, 32), 256, 0, stream>>>(attno, WoT, out, 4096, 2048, 2048);
}